// Round 6
// baseline (29.493 us; speedup 1.0000x reference)
//
#include <hip/hip_runtime.h>
#include <math.h>

#define BB 2
#define SS 256
#define DD 256
#define EPSF 1e-6f

__device__ __forceinline__ float wave_scan_sum(float v, int lane) {
#pragma unroll
    for (int o = 1; o < 64; o <<= 1) {
        float u = __shfl_up(v, o);
        if (lane >= o) v += u;
    }
    return v;
}
__device__ __forceinline__ float wave_scan_prod(float v, int lane) {
#pragma unroll
    for (int o = 1; o < 64; o <<= 1) {
        float u = __shfl_up(v, o);
        if (lane >= o) v *= u;
    }
    return v;
}

// One kernel, no grid sync, 32 blocks x 1024 threads.
// Phase A: each wave computes LN-dots for 16 rows in 4 groups of 4
// (double-buffered prefetch, 16 interleaved shfl chains, ~80 VGPR — no spill).
// Phase B: wave wv emits output row i0+wv.
__global__ __launch_bounds__(1024, 1) void fused(
        const float* __restrict__ ctx,
        const float* __restrict__ ln_g, const float* __restrict__ ln_b,
        const float* __restrict__ fc_w, const float* __restrict__ prior,
        const float* __restrict__ fc_b,
        float* __restrict__ G, float* __restrict__ Mij) {
    __shared__ float dx1s[SS], dx2s[SS], P2s[SS];
    __shared__ float parts[4];

    const int t = threadIdx.x, wv = t >> 6, lane = t & 63;
    const int b  = blockIdx.x >> 4;
    const int i0 = (blockIdx.x & 15) << 4;

    const float pr = prior[0], fb = fc_b[0];

    const float4 g   = ((const float4*)ln_g)[lane];
    const float4 bbv = ((const float4*)ln_b)[lane];
    const float4 w1  = ((const float4*)fc_w)[lane];
    const float4 w2  = ((const float4*)fc_w)[64 + lane];
    const float gw1x = g.x * w1.x, gw1y = g.y * w1.y, gw1z = g.z * w1.z, gw1w = g.w * w1.w;
    const float gw2x = g.x * w2.x, gw2y = g.y * w2.y, gw2z = g.z * w2.z, gw2w = g.w * w2.w;

    float sg1 = gw1x + gw1y + gw1z + gw1w;
    float sg2 = gw2x + gw2y + gw2z + gw2w;
    float cb1 = bbv.x * w1.x + bbv.y * w1.y + bbv.z * w1.z + bbv.w * w1.w;
    float cb2 = bbv.x * w2.x + bbv.y * w2.y + bbv.z * w2.z + bbv.w * w2.w;
#pragma unroll
    for (int o = 32; o > 0; o >>= 1) {
        sg1 += __shfl_xor(sg1, o);
        sg2 += __shfl_xor(sg2, o);
        cb1 += __shfl_xor(cb1, o);
        cb2 += __shfl_xor(cb2, o);
    }

    // ---- Phase A: rows wv*16 .. wv*16+15, groups of 4, double-buffered ----
    const float4* base = ((const float4*)ctx) + (size_t)(b * SS + wv * 16) * 64 + lane;
    float4 cur[4], nxt[4];
#pragma unroll
    for (int j = 0; j < 4; ++j) cur[j] = base[j * 64];

#pragma unroll 1
    for (int grp = 0; grp < 4; ++grp) {
        if (grp < 3) {
            const float4* nb = base + (grp + 1) * 256;
#pragma unroll
            for (int j = 0; j < 4; ++j) nxt[j] = nb[j * 64];
        }
        float s0[4], s1[4], a1[4], a2[4];
#pragma unroll
        for (int j = 0; j < 4; ++j) {
            const float4 cc = cur[j];
            s0[j] = cc.x + cc.y + cc.z + cc.w;
            s1[j] = cc.x * cc.x + cc.y * cc.y + cc.z * cc.z + cc.w * cc.w;
            a1[j] = cc.x * gw1x + cc.y * gw1y + cc.z * gw1z + cc.w * gw1w;
            a2[j] = cc.x * gw2x + cc.y * gw2y + cc.z * gw2z + cc.w * gw2w;
        }
#pragma unroll
        for (int o = 32; o > 0; o >>= 1) {
#pragma unroll
            for (int j = 0; j < 4; ++j) {
                s0[j] += __shfl_xor(s0[j], o);
                s1[j] += __shfl_xor(s1[j], o);
                a1[j] += __shfl_xor(a1[j], o);
                a2[j] += __shfl_xor(a2[j], o);
            }
        }
        if (lane == 0) {
#pragma unroll
            for (int j = 0; j < 4; ++j) {
                const int k = wv * 16 + grp * 4 + j;
                const float mu  = s0[j] * (1.0f / DD);
                const float var = (s1[j] - DD * mu * mu) * (1.0f / (DD - 1));
                const float inv = 1.0f / (sqrtf(var) + EPSF);
                dx1s[k] = (a1[j] - mu * sg1) * inv + cb1;
                dx2s[k] = (a2[j] - mu * sg2) * inv + cb2;
            }
        }
#pragma unroll
        for (int j = 0; j < 4; ++j) cur[j] = nxt[j];
    }
    __syncthreads();

    // ---- block scan of dx2s -> P2s (waves 0-3 only) ----
    float incl = 0.0f;
    if (t < SS) {
        incl = wave_scan_sum(dx2s[t], lane);
        if (lane == 63) parts[wv] = incl;
    }
    __syncthreads();
    if (t < SS) {
        float pre = 0.0f;
        if (wv > 0) pre += parts[0];
        if (wv > 1) pre += parts[1];
        if (wv > 2) pre += parts[2];
        P2s[t] = incl + pre;
    }
    __syncthreads();

    // ---- Phase B: wave wv -> output row i = i0 + wv ----
    const float mconst = pr + (1.0f - pr) / (1.0f + expf(-fb));
    const int i = i0 + wv;
    const float base_p2 = (i > 0) ? P2s[i - 1] : 0.0f;
    float carry = 1.0f;
    float* Grow = G   + (size_t)(b * SS + i) * SS;
    float* Mrow = Mij + (size_t)(b * SS + i) * SS;
#pragma unroll
    for (int cc = 0; cc < 4; ++cc) {
        const int k = cc * 64 + lane;
        float m;
        if (k >= i) {
            const float l = dx1s[k] + (P2s[k] - base_p2) / (float)(k - i + 1) + fb;
            m = pr + (1.0f - pr) / (1.0f + expf(-l));
        } else {
            m = mconst;
        }
        Mrow[k] = m;
        const float v = (k >= i) ? m : 1.0f;
        const float p = wave_scan_prod(v, lane) * carry;
        carry = __shfl(p, 63);
        if (k == i) {
            Grow[k] = 1.0f;
        } else if (k > i) {
            Grow[k] = p;                              // row write, coalesced
            G[(size_t)(b * SS + k) * SS + i] = p;     // symmetric column write
        }
    }
}

extern "C" void kernel_launch(void* const* d_in, const int* in_sizes, int n_in,
                              void* d_out, int out_size, void* d_ws, size_t ws_size,
                              hipStream_t stream) {
    const float* ctx   = (const float*)d_in[0];
    // d_in[1] = eos_mask (unused by reference)
    const float* prior = (const float*)d_in[2];
    const float* ln_g  = (const float*)d_in[3];
    const float* ln_b  = (const float*)d_in[4];
    const float* fc_w  = (const float*)d_in[5];
    const float* fc_b  = (const float*)d_in[6];

    float* G   = (float*)d_out;                    // B*S*S
    float* Mij = (float*)d_out + BB * SS * SS;     // B*S*S

    fused<<<32, 1024, 0, stream>>>(ctx, ln_g, ln_b, fc_w, prior, fc_b, G, Mij);
}

// Round 7
// 13.080 us; speedup vs baseline: 2.2549x; 2.2549x over previous
//
#include <hip/hip_runtime.h>
#include <math.h>

#define BB 2
#define SS 256
#define DD 256
#define EPSF 1e-6f

__device__ __forceinline__ float wave_scan_sum(float v, int lane) {
#pragma unroll
    for (int o = 1; o < 64; o <<= 1) {
        float u = __shfl_up(v, o);
        if (lane >= o) v += u;
    }
    return v;
}
__device__ __forceinline__ float wave_scan_prod(float v, int lane) {
#pragma unroll
    for (int o = 1; o < 64; o <<= 1) {
        float u = __shfl_up(v, o);
        if (lane >= o) v *= u;
    }
    return v;
}

// K1: one wave per row. 8 interleaved wave reductions (ILP hides shfl latency).
// Writes packed {dx1, dx2} as float2 so K2 does a single 8B load per thread.
__global__ __launch_bounds__(256) void k1_lndots(
        const float* __restrict__ ctx,
        const float* __restrict__ ln_g, const float* __restrict__ ln_b,
        const float* __restrict__ fc_w,
        float2* __restrict__ dxp) {
    const int t = threadIdx.x, wv = t >> 6, lane = t & 63;
    const int r = blockIdx.x * 4 + wv;            // 128 blocks * 4 waves = 512 rows

    const float4 c  = ((const float4*)ctx)[r * 64 + lane];
    const float4 g  = ((const float4*)ln_g)[lane];
    const float4 bb = ((const float4*)ln_b)[lane];
    const float4 w1 = ((const float4*)fc_w)[lane];
    const float4 w2 = ((const float4*)fc_w)[64 + lane];

    const float gw1x = g.x * w1.x, gw1y = g.y * w1.y, gw1z = g.z * w1.z, gw1w = g.w * w1.w;
    const float gw2x = g.x * w2.x, gw2y = g.y * w2.y, gw2z = g.z * w2.z, gw2w = g.w * w2.w;

    float s0  = c.x + c.y + c.z + c.w;
    float s1  = c.x * c.x + c.y * c.y + c.z * c.z + c.w * c.w;
    float a1  = c.x * gw1x + c.y * gw1y + c.z * gw1z + c.w * gw1w;
    float a2  = c.x * gw2x + c.y * gw2y + c.z * gw2z + c.w * gw2w;
    float sg1 = gw1x + gw1y + gw1z + gw1w;
    float sg2 = gw2x + gw2y + gw2z + gw2w;
    float cb1 = bb.x * w1.x + bb.y * w1.y + bb.z * w1.z + bb.w * w1.w;
    float cb2 = bb.x * w2.x + bb.y * w2.y + bb.z * w2.z + bb.w * w2.w;

#pragma unroll
    for (int o = 32; o > 0; o >>= 1) {            // 8 reductions interleaved
        s0  += __shfl_xor(s0, o);
        s1  += __shfl_xor(s1, o);
        a1  += __shfl_xor(a1, o);
        a2  += __shfl_xor(a2, o);
        sg1 += __shfl_xor(sg1, o);
        sg2 += __shfl_xor(sg2, o);
        cb1 += __shfl_xor(cb1, o);
        cb2 += __shfl_xor(cb2, o);
    }

    if (lane == 0) {
        const float mu  = s0 * (1.0f / DD);
        const float var = (s1 - DD * mu * mu) * (1.0f / (DD - 1));
        const float inv = 1.0f / (sqrtf(var) + EPSF);
        dxp[r] = make_float2((a1 - mu * sg1) * inv + cb1,
                             (a2 - mu * sg2) * inv + cb2);
    }
}

// K2: block = output row (b,i). Local scan of dx2 (L2-hot), Mij, product scan, G.
__global__ __launch_bounds__(256) void k2_mg(
        const float2* __restrict__ dxp,
        const float* __restrict__ prior, const float* __restrict__ fc_b,
        float* __restrict__ G, float* __restrict__ Mij) {
    __shared__ float P2s[SS];
    __shared__ float parts_s[4];
    __shared__ float parts_p[4];

    const int r = blockIdx.x;                     // b*S + i
    const int b = r >> 8, i = r & 255;
    const int t = threadIdx.x, wv = t >> 6, lane = t & 63;

    const float pr = prior[0], fb = fc_b[0];      // in flight early
    const float2 dd = dxp[b * SS + t];
    const float d1 = dd.x, d2 = dd.y;

    // block-wide inclusive sum scan of d2
    float incl = wave_scan_sum(d2, lane);
    if (lane == 63) parts_s[wv] = incl;
    __syncthreads();
#pragma unroll
    for (int j = 0; j < 3; ++j)
        if (wv > j) incl += parts_s[j];
    P2s[t] = incl;
    __syncthreads();

    const float base = (i > 0) ? P2s[i - 1] : 0.0f;

    float m;
    if (t >= i) {
        const float l = d1 + (incl - base) / (float)(t - i + 1) + fb;
        m = pr + (1.0f - pr) / (1.0f + __expf(-l));
    } else {
        m = pr + (1.0f - pr) / (1.0f + __expf(-fb));
    }
    Mij[r * SS + t] = m;

    // block-wide inclusive product scan of v
    const float v = (t >= i) ? m : 1.0f;
    float pincl = wave_scan_prod(v, lane);
    if (lane == 63) parts_p[wv] = pincl;
    __syncthreads();
#pragma unroll
    for (int j = 0; j < 3; ++j)
        if (wv > j) pincl *= parts_p[j];

    if (t == i) {
        G[r * SS + t] = 1.0f;
    } else if (t > i) {
        G[r * SS + t] = pincl;                        // row write, coalesced
        G[(size_t)(b * SS + t) * SS + i] = pincl;     // symmetric column write
    }
}

extern "C" void kernel_launch(void* const* d_in, const int* in_sizes, int n_in,
                              void* d_out, int out_size, void* d_ws, size_t ws_size,
                              hipStream_t stream) {
    const float* ctx   = (const float*)d_in[0];
    // d_in[1] = eos_mask (unused by reference)
    const float* prior = (const float*)d_in[2];
    const float* ln_g  = (const float*)d_in[3];
    const float* ln_b  = (const float*)d_in[4];
    const float* fc_w  = (const float*)d_in[5];
    const float* fc_b  = (const float*)d_in[6];

    float* G   = (float*)d_out;                    // B*S*S
    float* Mij = (float*)d_out + BB * SS * SS;     // B*S*S

    float2* dxp = (float2*)d_ws;                   // B*S packed {dx1,dx2}

    k1_lndots<<<BB * SS / 4, 256, 0, stream>>>(ctx, ln_g, ln_b, fc_w, dxp);
    k2_mg<<<BB * SS, 256, 0, stream>>>(dxp, prior, fc_b, G, Mij);
}